// Round 11
// baseline (128.202 us; speedup 1.0000x reference)
//
#include <hip/hip_runtime.h>
#include <hip/hip_bf16.h>

// Problem constants: B=4, C=256, N=4096, G=8, NH=8, HD=32, M=512
#define Bb 4
#define Cc 256
#define Nn 4096
#define Gg 8
#define NHh 8
#define HDd 32
#define Mm 512

typedef __bf16 bf16_t;
typedef __bf16 bf16x2 __attribute__((ext_vector_type(2)));
typedef __bf16 bf16x4 __attribute__((ext_vector_type(4)));
typedef __bf16 bf16x8 __attribute__((ext_vector_type(8)));
typedef float f32x4 __attribute__((ext_vector_type(4)));

// hd^-0.5 * log2(e): folded into Q at the QKV epilogue so attn's
// exponent is plain exp2(S).
#define LSCALE (0.17677669529663687f * 1.44269504088896340f)

__device__ __forceinline__ void load_lds16(const bf16_t* g, bf16_t* l) {
  __builtin_amdgcn_global_load_lds(
      (const __attribute__((address_space(1))) void*)g,
      (__attribute__((address_space(3))) void*)l, 16, 0, 0);
}

// ------------------------------------- prep: transpose+cast x, cast weights
// blocks [0,1024): 64x64 transpose tiles of x -> xT [B][N][C] bf16
// blocks [1024,1792): weight casts
__global__ __launch_bounds__(256) void prep_kernel(
    const float* __restrict__ x, bf16_t* __restrict__ xT,
    const float* __restrict__ wqkv, const float* __restrict__ wproj,
    bf16_t* __restrict__ wq_b, bf16_t* __restrict__ wp_b) {
  int bid = blockIdx.x, tid = threadIdx.x;
  if (bid >= 1024) {
    int i = (bid - 1024) * 256 + tid;
    wq_b[i] = (bf16_t)wqkv[i];
    if (i < Cc * Cc) wp_b[i] = (bf16_t)wproj[i];
    return;
  }
  __shared__ float t[64][65];
  int b = bid >> 8, c0 = ((bid >> 6) & 3) * 64, n0 = (bid & 63) * 64;
  const float* xp = x + ((long long)b * Cc + c0) * Nn + n0;
#pragma unroll
  for (int it = 0; it < 4; ++it) {
    int idx = it * 256 + tid;          // [0,1024)
    int r = idx >> 4, col = (idx & 15) * 4;   // r = c offset, col = n offset
    f32x4 v = *(const f32x4*)&xp[(long long)r * Nn + col];
    t[r][col] = v[0];
    t[r][col + 1] = v[1];
    t[r][col + 2] = v[2];
    t[r][col + 3] = v[3];
  }
  __syncthreads();
  bf16_t* op = xT + ((long long)b * Nn + n0) * Cc + c0;
#pragma unroll
  for (int it = 0; it < 2; ++it) {
    int idx = it * 256 + tid;          // [0,512)
    int n = idx >> 3, cg = (idx & 7) * 8;     // n = n offset, cg = c offset
    bf16x8 w;
#pragma unroll
    for (int j = 0; j < 8; ++j) w[j] = (bf16_t)t[cg + j][n];
    *(bf16x8*)&op[(long long)n * Cc + cg] = w;
  }
}

// --------------------------------------------- QKV GEMM (R17: barrier-free)
// BM=64 x BN=256 (3 n-tiles: 0=Q,1=K,2=V — block-uniform epilogue).
// R17: A (xT tile, the reused operand) staged ONCE in LDS at row stride 266
// (odd dword count -> ds_read_b128 fragments land ~2-way on banks; the old
// [row][32] layout was 8-way = 2.9x, SQ_LDS_BANK_CONFLICT 1.26e7 in R11).
// B (weights, 384KB L2-hot) streamed global->registers: the K-loop has ZERO
// barriers — no correlated vmcnt(0) drains (the R9-R16 structural stall).
// Epilogue: R15/R16 coalesced LDS-transpose stores (full 64B lines).
__global__ __launch_bounds__(256, 4) void qkv_gemm_kernel(
    const bf16_t* __restrict__ xT, const bf16_t* __restrict__ wqb,
    bf16_t* __restrict__ Qh, bf16_t* __restrict__ Kh, bf16_t* __restrict__ Vh) {
  // 36.9KB: A-tile [64][266]=17024; epilogue reuse Q/K T[64][268]=17152,
  // V T[256][72]=18432 (max index 18423).
  __shared__ bf16_t smem[18432];
  int bid = blockIdx.x;
  int m0 = (bid / 3) * 64;             // 256 m-tiles over 16384 (b,n) rows
  int n0 = (bid % 3) * 256;            // 0=Q, 256=K, 512=V
  int tid = threadIdx.x, lane = tid & 63, wid = tid >> 6;
  int quad = lane >> 4, l16 = lane & 15;
  int wn = wid * 64;                   // wave's 64-col slice of the 256

  // ---- stage A fully (one barrier total): 4 threads/row, 8x16B each
  {
    int row = tid >> 2, seg = tid & 3;
    const bf16_t* src = &xT[(long long)(m0 + row) * Cc + seg * 64];
    bf16x8 tmp[8];
#pragma unroll
    for (int j = 0; j < 8; ++j) tmp[j] = *(const bf16x8*)&src[j * 8];
#pragma unroll
    for (int j = 0; j < 8; ++j)
      *(bf16x8*)&smem[row * 266 + seg * 64 + j * 8] = tmp[j];
  }

  f32x4 acc[4][4];
#pragma unroll
  for (int i = 0; i < 4; ++i)
#pragma unroll
    for (int j = 0; j < 4; ++j) acc[i][j] = (f32x4){0.f, 0.f, 0.f, 0.f};

  __syncthreads();

  // ---- K-loop: no barriers; b-loads pipelined by the compiler under MFMAs
  const bf16_t* Bw = wqb + (long long)n0 * Cc;
#pragma unroll
  for (int t = 0; t < 8; ++t) {
    int k0 = t * 32;
    bf16x8 a[4], b[4];
#pragma unroll
    for (int j = 0; j < 4; ++j)
      b[j] = *(const bf16x8*)&Bw[(long long)(wn + j * 16 + l16) * Cc + k0 + quad * 8];
#pragma unroll
    for (int i = 0; i < 4; ++i)
      a[i] = *(const bf16x8*)&smem[(i * 16 + l16) * 266 + k0 + quad * 8];
#pragma unroll
    for (int i = 0; i < 4; ++i)
#pragma unroll
      for (int j = 0; j < 4; ++j)
        acc[i][j] = __builtin_amdgcn_mfma_f32_16x16x32_bf16(a[i], b[j], acc[i][j], 0, 0, 0);
  }
  __syncthreads();                     // A-reads done; smem reusable

  if (n0 < 512) {
    const bool isQ = (n0 == 0);
    const float s = isQ ? LSCALE : 1.0f;
    // Transpose through LDS: T[m_local][f], stride 268.
#pragma unroll
    for (int i = 0; i < 4; ++i)
#pragma unroll
      for (int j = 0; j < 4; ++j) {
        int f = wn + j * 16 + l16;
#pragma unroll
        for (int r = 0; r < 4; ++r) {
          int lm = i * 16 + quad * 4 + r;
          smem[lm * 268 + f] = (bf16_t)(acc[i][j][r] * s);
        }
      }
    __syncthreads();
    // Coalesced row stores: 4 lanes cover one 64B row (m, d0..d0+7 x4).
    int lm = tid >> 2, d0 = (tid & 3) * 8;
    int row = m0 + lm;
    int bb = row >> 12, gg = (row >> 9) & 7, m = row & 511;
    bf16_t* dst = isQ ? Qh : Kh;
#pragma unroll
    for (int hh = 0; hh < 8; ++hh) {
      long long hb = (long long)((bb << 6) | (gg << 3) | hh) * (Mm * HDd);
      bf16x8 w = *(bf16x8*)&smem[lm * 268 + hh * 32 + d0];
      *(bf16x8*)&dst[hb + m * HDd + d0] = w;
    }
  } else {
    // V^T through LDS: T[f][m_local], stride 72; full-line bf16x8 stores.
#pragma unroll
    for (int i = 0; i < 4; ++i)
#pragma unroll
      for (int j = 0; j < 4; ++j) {
        int f = wn + j * 16 + l16;
#pragma unroll
        for (int r = 0; r < 4; ++r)
          smem[f * 72 + i * 16 + quad * 4 + r] = (bf16_t)acc[i][j][r];
      }
    __syncthreads();
    int bb = m0 >> 12, gg = (m0 >> 9) & 7, mb = m0 & 511;
#pragma unroll
    for (int it = 0; it < 8; ++it) {
      int idx = it * 256 + tid;          // [0,2048)
      int f = idx >> 3, seg = idx & 7;   // f in [0,256), seg in [0,8)
      int hh = f >> 5, d = f & 31;
      long long hb = (long long)((bb << 6) | (gg << 3) | hh) * (Mm * HDd);
      bf16x8 w = *(bf16x8*)&smem[f * 72 + seg * 8];
      *(bf16x8*)&Vh[hb + (long long)d * Mm + mb + seg * 8] = w;
    }
  }
}

// ------------------------------------------------------------------ attention
// R16 structure (validated): 1024 blocks (head*4 + ms, 128 Q rows each),
// 4 waves, 32 q-rows/wave; K/V staged in halves; phase-1 V prefetched to
// regs during phase-0 staging; ones-MFMA softmax denominator.
__global__ __launch_bounds__(256, 4) void attn_kernel(
    const bf16_t* __restrict__ Qh, const bf16_t* __restrict__ Kh,
    const bf16_t* __restrict__ Vh, bf16_t* __restrict__ Oa) {
  __shared__ bf16_t Ks[256 * 32];      // K half (16KB)
  __shared__ bf16_t Vs[32 * 264];      // V half, rows padded to 264 (16.5KB)
  int gid = blockIdx.x;
  int ms = gid & 3, head = gid >> 2;
  int h = head & 7, g = (head >> 3) & 7, b = head >> 6;
  int tid = threadIdx.x, lane = tid & 63, wid = tid >> 6;
  int quad = lane >> 4, l16 = lane & 15;

  const bf16_t* Kg = Kh + (long long)head * (Mm * HDd);
  const bf16_t* Vg = Vh + (long long)head * (Mm * HDd);
  const bf16_t* Qg = Qh + (long long)head * (Mm * HDd) + (ms * 128 + wid * 32) * HDd;

  // Q fragments: phase-invariant, loaded once.
  bf16x8 qa = *(const bf16x8*)&Qg[l16 * HDd + quad * 8];
  bf16x8 qb = *(const bf16x8*)&Qg[(16 + l16) * HDd + quad * 8];

  bf16x8 ones;
#pragma unroll
  for (int i = 0; i < 8; ++i) ones[i] = (bf16_t)1.0f;

  // Permuted K-row gather: tile0 rows 8q+r, tile1 rows 8q+4+r
  int rp0 = ((l16 >> 2) << 3) | (l16 & 3);
  const bf16_t* Kp0 = &Ks[rp0 * HDd + quad * 8];        // +c*1024 per chunk
  const bf16_t* Kp1 = Kp0 + 4 * HDd;
  const bf16_t* VsL = &Vs[l16 * 264 + quad * 8];
  const bf16_t* VsH = &Vs[(16 + l16) * 264 + quad * 8];
  const f32x4 zero = (f32x4){0.f, 0.f, 0.f, 0.f};

  f32x4 oLa = zero, oHa = zero, oLb = zero, oHb = zero;
  f32x4 ra = zero, rb = zero;

  auto inner = [&]() {
#pragma unroll
    for (int c = 0; c < 8; ++c) {       // 32 K-rows per chunk
      int nb = c * 32;
      bf16x8 kf0 = *(const bf16x8*)&Kp0[nb * HDd];
      bf16x8 kf1 = *(const bf16x8*)&Kp1[nb * HDd];
      f32x4 sa0 = __builtin_amdgcn_mfma_f32_16x16x32_bf16(kf0, qa, zero, 0, 0, 0);
      f32x4 sa1 = __builtin_amdgcn_mfma_f32_16x16x32_bf16(kf1, qa, zero, 0, 0, 0);
      f32x4 sb0 = __builtin_amdgcn_mfma_f32_16x16x32_bf16(kf0, qb, zero, 0, 0, 0);
      f32x4 sb1 = __builtin_amdgcn_mfma_f32_16x16x32_bf16(kf1, qb, zero, 0, 0, 0);
      bf16x8 pa, pb;
#pragma unroll
      for (int r = 0; r < 4; ++r) {
        pa[r] = (bf16_t)__builtin_exp2f(sa0[r]);
        pa[4 + r] = (bf16_t)__builtin_exp2f(sa1[r]);
        pb[r] = (bf16_t)__builtin_exp2f(sb0[r]);
        pb[4 + r] = (bf16_t)__builtin_exp2f(sb1[r]);
      }
      bf16x8 vL = *(const bf16x8*)&VsL[nb];
      bf16x8 vH = *(const bf16x8*)&VsH[nb];
      oLa = __builtin_amdgcn_mfma_f32_16x16x32_bf16(vL, pa, oLa, 0, 0, 0);
      oHa = __builtin_amdgcn_mfma_f32_16x16x32_bf16(vH, pa, oHa, 0, 0, 0);
      oLb = __builtin_amdgcn_mfma_f32_16x16x32_bf16(vL, pb, oLb, 0, 0, 0);
      oHb = __builtin_amdgcn_mfma_f32_16x16x32_bf16(vH, pb, oHb, 0, 0, 0);
      ra = __builtin_amdgcn_mfma_f32_16x16x32_bf16(ones, pa, ra, 0, 0, 0);
      rb = __builtin_amdgcn_mfma_f32_16x16x32_bf16(ones, pb, rb, 0, 0, 0);
    }
  };

  // ---- phase 0 staging (block start: LDS cold, no WAR barrier needed)
#pragma unroll
  for (int it = 0; it < 4; ++it) {
    int ch = wid * 4 + it;
    load_lds16(&Kg[ch * 512 + lane * 8], &Ks[ch * 512]);
  }
  bf16x8 vcur[4], vnxt[4];
#pragma unroll
  for (int i = 0; i < 4; ++i) {
    int idx = i * 256 + tid;
    int d = idx >> 5, c16 = idx & 31;
    vcur[i] = *(const bf16x8*)&Vg[d * Mm + c16 * 8];
    vnxt[i] = *(const bf16x8*)&Vg[d * Mm + 256 + c16 * 8];  // prefetch
  }
#pragma unroll
  for (int i = 0; i < 4; ++i) {
    int idx = i * 256 + tid;
    int d = idx >> 5, c16 = idx & 31;
    *(bf16x8*)&Vs[d * 264 + c16 * 8] = vcur[i];
  }
  __syncthreads();
  inner();                              // phase 0
  __syncthreads();                      // Ks/Vs WAR
  // ---- phase 1 staging (V already in regs)
#pragma unroll
  for (int it = 0; it < 4; ++it) {
    int ch = wid * 4 + it;
    load_lds16(&Kg[8192 + ch * 512 + lane * 8], &Ks[ch * 512]);
  }
#pragma unroll
  for (int i = 0; i < 4; ++i) {
    int idx = i * 256 + tid;
    int d = idx >> 5, c16 = idx & 31;
    *(bf16x8*)&Vs[d * 264 + c16 * 8] = vnxt[i];
  }
  __syncthreads();
  inner();                              // phase 1

  // denom: every component of ra equals sum_n P[n][l16]
  float inva = 1.f / ra[0], invb = 1.f / rb[0];

  // O^T in C-layout: lane holds O^T[d=quad*4+r (+0/16)][m=l16]
  long long orowa =
      ((long long)(b * Nn + g * Mm + ms * 128 + wid * 32 + l16)) * Cc + h * HDd;
  long long orowb = orowa + 16 * Cc;
  bf16x4 wLa, wHa, wLb, wHb;
#pragma unroll
  for (int r = 0; r < 4; ++r) {
    wLa[r] = (bf16_t)(oLa[r] * inva);
    wHa[r] = (bf16_t)(oHa[r] * inva);
    wLb[r] = (bf16_t)(oLb[r] * invb);
    wHb[r] = (bf16_t)(oHb[r] * invb);
  }
  *(bf16x4*)&Oa[orowa + quad * 4] = wLa;
  *(bf16x4*)&Oa[orowa + 16 + quad * 4] = wHa;
  *(bf16x4*)&Oa[orowb + quad * 4] = wLb;
  *(bf16x4*)&Oa[orowb + 16 + quad * 4] = wHb;
}

// ----------------------------------------------------------------- proj GEMM
// out[b][i][n] = sum_c Wp[i][c]*Oa[b*N+n][c] + bias[i]; z-batched over b.
// R17: same barrier-free template as qkv — Oa tile [64 n][256 c] staged once
// (stride 266, ~2-way banks), Wp (128KB L2-hot) streamed direct to regs.
// Tile 128i x 64n, grid dim3(64,2,4) = 512 blocks = 2/CU.
__global__ __launch_bounds__(256, 4) void proj_kernel(
    const bf16_t* __restrict__ Wp, const bf16_t* __restrict__ Oa,
    float* __restrict__ out, const float* __restrict__ bias) {
  __shared__ bf16_t smem[64 * 266];    // 34 KB
  int tid = threadIdx.x, lane = tid & 63, wid = tid >> 6;
  int quad = lane >> 4, l16 = lane & 15;
  int z = blockIdx.z;
  int n0 = blockIdx.x * 64, i0 = blockIdx.y * 128;
  const bf16_t* Bt = Oa + (long long)z * Nn * Cc;

  // stage Oa tile [64 n][256 c], stride 266
  {
    int row = tid >> 2, seg = tid & 3;
    const bf16_t* src = &Bt[(long long)(n0 + row) * Cc + seg * 64];
    bf16x8 tmp[8];
#pragma unroll
    for (int j = 0; j < 8; ++j) tmp[j] = *(const bf16x8*)&src[j * 8];
#pragma unroll
    for (int j = 0; j < 8; ++j)
      *(bf16x8*)&smem[row * 266 + seg * 64 + j * 8] = tmp[j];
  }

  f32x4 acc[2][4];
#pragma unroll
  for (int i = 0; i < 2; ++i)
#pragma unroll
    for (int j = 0; j < 4; ++j) acc[i][j] = (f32x4){0.f, 0.f, 0.f, 0.f};

  __syncthreads();

  int wm = i0 + wid * 32;              // wave's 32 features
#pragma unroll
  for (int t = 0; t < 8; ++t) {
    int k0 = t * 32;
    bf16x8 a[2], b[4];
#pragma unroll
    for (int i = 0; i < 2; ++i)
      a[i] = *(const bf16x8*)&Wp[(long long)(wm + i * 16 + l16) * Cc + k0 + quad * 8];
#pragma unroll
    for (int j = 0; j < 4; ++j)
      b[j] = *(const bf16x8*)&smem[(j * 16 + l16) * 266 + k0 + quad * 8];
#pragma unroll
    for (int i = 0; i < 2; ++i)
#pragma unroll
      for (int j = 0; j < 4; ++j)
        acc[i][j] = __builtin_amdgcn_mfma_f32_16x16x32_bf16(a[i], b[j], acc[i][j], 0, 0, 0);
  }

#pragma unroll
  for (int i = 0; i < 2; ++i) {
#pragma unroll
    for (int j = 0; j < 4; ++j) {
      int col = n0 + j * 16 + l16;
#pragma unroll
      for (int r = 0; r < 4; ++r) {
        int row = wm + i * 16 + quad * 4 + r;
        out[(long long)z * (Cc * Nn) + (long long)row * Nn + col] =
            acc[i][j][r] + bias[row];
      }
    }
  }
}

// ------------------------------------------------------------------- launcher
extern "C" void kernel_launch(void* const* d_in, const int* in_sizes, int n_in,
                              void* d_out, int out_size, void* d_ws, size_t ws_size,
                              hipStream_t stream) {
  (void)in_sizes; (void)n_in; (void)out_size; (void)ws_size;
  const float* x = (const float*)d_in[0];
  const float* w_qkv = (const float*)d_in[1];
  const float* w_proj = (const float*)d_in[2];
  const float* b_proj = (const float*)d_in[3];
  float* out = (float*)d_out;

  char* ws = (char*)d_ws;
  bf16_t* xT  = (bf16_t*)(ws);                 // [B][N][C]     8,388,608 B
  bf16_t* wqb = (bf16_t*)(ws + 8388608);       // [768][256]      393,216 B
  bf16_t* wpb = (bf16_t*)(ws + 8781824);       // [256][256]      131,072 B
  bf16_t* Qh  = (bf16_t*)(ws + 8912896);       // [256][512][32] 8,388,608 B
  bf16_t* Kh  = (bf16_t*)(ws + 17301504);      // [256][512][32] 8,388,608 B
  bf16_t* Vh  = (bf16_t*)(ws + 25690112);      // [256][32][512] 8,388,608 B
  bf16_t* Oa  = (bf16_t*)(ws + 34078720);      // [B*N][256]     8,388,608 B

  prep_kernel<<<1792, 256, 0, stream>>>(x, xT, w_qkv, w_proj, wqb, wpb);
  qkv_gemm_kernel<<<768, 256, 0, stream>>>(xT, wqb, Qh, Kh, Vh);
  attn_kernel<<<1024, 256, 0, stream>>>(Qh, Kh, Vh, Oa);
  proj_kernel<<<dim3(64, 2, 4), 256, 0, stream>>>(wpb, Oa, out, b_proj);
}

// Round 12
// 117.837 us; speedup vs baseline: 1.0880x; 1.0880x over previous
//
#include <hip/hip_runtime.h>
#include <hip/hip_bf16.h>

// Problem constants: B=4, C=256, N=4096, G=8, NH=8, HD=32, M=512
#define Bb 4
#define Cc 256
#define Nn 4096
#define Gg 8
#define NHh 8
#define HDd 32
#define Mm 512

typedef __bf16 bf16_t;
typedef __bf16 bf16x2 __attribute__((ext_vector_type(2)));
typedef __bf16 bf16x4 __attribute__((ext_vector_type(4)));
typedef __bf16 bf16x8 __attribute__((ext_vector_type(8)));
typedef float f32x4 __attribute__((ext_vector_type(4)));

// hd^-0.5 * log2(e): folded into Q at the QKV epilogue so attn's
// exponent is plain exp2(S).
#define LSCALE (0.17677669529663687f * 1.44269504088896340f)

__device__ __forceinline__ void load_lds16(const bf16_t* g, bf16_t* l) {
  __builtin_amdgcn_global_load_lds(
      (const __attribute__((address_space(1))) void*)g,
      (__attribute__((address_space(3))) void*)l, 16, 0, 0);
}

// ------------------------------------- prep: transpose+cast x, cast weights
// blocks [0,1024): 64x64 transpose tiles of x -> xT [B][N][C] bf16
// blocks [1024,1792): weight casts
__global__ __launch_bounds__(256) void prep_kernel(
    const float* __restrict__ x, bf16_t* __restrict__ xT,
    const float* __restrict__ wqkv, const float* __restrict__ wproj,
    bf16_t* __restrict__ wq_b, bf16_t* __restrict__ wp_b) {
  int bid = blockIdx.x, tid = threadIdx.x;
  if (bid >= 1024) {
    int i = (bid - 1024) * 256 + tid;
    wq_b[i] = (bf16_t)wqkv[i];
    if (i < Cc * Cc) wp_b[i] = (bf16_t)wproj[i];
    return;
  }
  __shared__ float t[64][65];
  int b = bid >> 8, c0 = ((bid >> 6) & 3) * 64, n0 = (bid & 63) * 64;
  const float* xp = x + ((long long)b * Cc + c0) * Nn + n0;
#pragma unroll
  for (int it = 0; it < 4; ++it) {
    int idx = it * 256 + tid;          // [0,1024)
    int r = idx >> 4, col = (idx & 15) * 4;   // r = c offset, col = n offset
    f32x4 v = *(const f32x4*)&xp[(long long)r * Nn + col];
    t[r][col] = v[0];
    t[r][col + 1] = v[1];
    t[r][col + 2] = v[2];
    t[r][col + 3] = v[3];
  }
  __syncthreads();
  bf16_t* op = xT + ((long long)b * Nn + n0) * Cc + c0;
#pragma unroll
  for (int it = 0; it < 2; ++it) {
    int idx = it * 256 + tid;          // [0,512)
    int n = idx >> 3, cg = (idx & 7) * 8;     // n = n offset, cg = c offset
    bf16x8 w;
#pragma unroll
    for (int j = 0; j < 8; ++j) w[j] = (bf16_t)t[cg + j][n];
    *(bf16x8*)&op[(long long)n * Cc + cg] = w;
  }
}

// --------------------------------------------- QKV GEMM (unified + R16/R18)
// BM=64 x BN=256 (3 n-tiles: 0=Q,1=K,2=V — block-uniform epilogue).
// R15/R16: coalesced LDS-transpose epilogues (full 64B-line stores).
// R18: XCD-chunked block swizzle — logical blocks 3g..3g+2 share the same
// 32KB A-tile; default round-robin puts them on 3 different XCD L2s (A read
// 3x from L3). Remap bid=(phys&7)*96+phys>>3 (bijective, 768=8x96)
// co-locates sharers on one XCD -> 2 of 3 A-reads become local L2 hits.
__global__ __launch_bounds__(256, 4) void qkv_gemm_kernel(
    const bf16_t* __restrict__ xT, const bf16_t* __restrict__ wqb,
    bf16_t* __restrict__ Qh, bf16_t* __restrict__ Kh, bf16_t* __restrict__ Vh) {
  // 40KB shared: staging As 2x2048 @0, Bs 2x8192 @4096.
  // Epilogue reuse: Q/K T[64][268] (17140 bf16); V T[256][72] (18423 bf16).
  __shared__ bf16_t smem[20480];
  int pb = blockIdx.x;
  int bid = (pb & 7) * 96 + (pb >> 3);   // R18 XCD-chunked swizzle
  int m0 = (bid / 3) * 64;             // 256 m-tiles over 16384 (b,n) rows
  int n0 = (bid % 3) * 256;            // 0=Q, 256=K, 512=V
  int tid = threadIdx.x, lane = tid & 63, wid = tid >> 6;
  int quad = lane >> 4, l16 = lane & 15;
  int wn = wid * 64;                   // wave's 64-col slice of the 256

  f32x4 acc[4][4];
#pragma unroll
  for (int i = 0; i < 4; ++i)
#pragma unroll
    for (int j = 0; j < 4; ++j) acc[i][j] = (f32x4){0.f, 0.f, 0.f, 0.f};

  int scol = (lane & 3) * 8;
  int arow = lane >> 2;                // 0..15
  auto stage = [&](int bufi, int k0) {
    load_lds16(&xT[(long long)(m0 + wid * 16 + arow) * Cc + k0 + scol],
               &smem[bufi * 2048 + wid * 512]);
#pragma unroll
    for (int r = 0; r < 4; ++r) {
      int ch = wid * 4 + r;
      load_lds16(&wqb[(long long)(n0 + ch * 16 + arow) * Cc + k0 + scol],
                 &smem[4096 + bufi * 8192 + ch * 512]);
    }
  };

  stage(0, 0);
  __syncthreads();                    // drain prologue staging
  for (int t = 0; t < 8; ++t) {
    if (t < 7) stage((t + 1) & 1, (t + 1) * 32);   // prefetch next step
    const bf16_t* Ap = &smem[(t & 1) * 2048];
    const bf16_t* Bp = &smem[4096 + (t & 1) * 8192];
    bf16x8 a[4], b[4];
#pragma unroll
    for (int i = 0; i < 4; ++i)
      a[i] = *(const bf16x8*)&Ap[(i * 16 + l16) * 32 + quad * 8];
#pragma unroll
    for (int j = 0; j < 4; ++j)
      b[j] = *(const bf16x8*)&Bp[(wn + j * 16 + l16) * 32 + quad * 8];
#pragma unroll
    for (int i = 0; i < 4; ++i)
#pragma unroll
      for (int j = 0; j < 4; ++j)
        acc[i][j] = __builtin_amdgcn_mfma_f32_16x16x32_bf16(a[i], b[j], acc[i][j], 0, 0, 0);
    __syncthreads();                  // next buf ready; this buf reusable
    // (final iteration's barrier also makes smem safe for the epilogue)
  }

  if (n0 < 512) {
    const bool isQ = (n0 == 0);
    const float s = isQ ? LSCALE : 1.0f;
    // Transpose through LDS: T[m_local][f], stride 268.
#pragma unroll
    for (int i = 0; i < 4; ++i)
#pragma unroll
      for (int j = 0; j < 4; ++j) {
        int f = wn + j * 16 + l16;
#pragma unroll
        for (int r = 0; r < 4; ++r) {
          int lm = i * 16 + quad * 4 + r;
          smem[lm * 268 + f] = (bf16_t)(acc[i][j][r] * s);
        }
      }
    __syncthreads();
    // Coalesced row stores: 4 lanes cover one 64B row (m, d0..d0+7 x4).
    int lm = tid >> 2, d0 = (tid & 3) * 8;
    int row = m0 + lm;
    int bb = row >> 12, gg = (row >> 9) & 7, m = row & 511;
    bf16_t* dst = isQ ? Qh : Kh;
#pragma unroll
    for (int hh = 0; hh < 8; ++hh) {
      long long hb = (long long)((bb << 6) | (gg << 3) | hh) * (Mm * HDd);
      bf16x8 w = *(bf16x8*)&smem[lm * 268 + hh * 32 + d0];
      *(bf16x8*)&dst[hb + m * HDd + d0] = w;
    }
  } else {
    // V^T through LDS: T[f][m_local], stride 72; full-line bf16x8 stores.
#pragma unroll
    for (int i = 0; i < 4; ++i)
#pragma unroll
      for (int j = 0; j < 4; ++j) {
        int f = wn + j * 16 + l16;
#pragma unroll
        for (int r = 0; r < 4; ++r)
          smem[f * 72 + i * 16 + quad * 4 + r] = (bf16_t)acc[i][j][r];
      }
    __syncthreads();
    int bb = m0 >> 12, gg = (m0 >> 9) & 7, mb = m0 & 511;
#pragma unroll
    for (int it = 0; it < 8; ++it) {
      int idx = it * 256 + tid;          // [0,2048)
      int f = idx >> 3, seg = idx & 7;   // f in [0,256), seg in [0,8)
      int hh = f >> 5, d = f & 31;
      long long hb = (long long)((bb << 6) | (gg << 3) | hh) * (Mm * HDd);
      bf16x8 w = *(bf16x8*)&smem[f * 72 + seg * 8];
      *(bf16x8*)&Vh[hb + (long long)d * Mm + mb + seg * 8] = w;
    }
  }
}

// ------------------------------------------------------------------ attention
// R16 structure (validated): 1024 blocks (head*4 + ms, 128 Q rows each),
// 4 waves, 32 q-rows/wave; K/V staged in halves; phase-1 V prefetched to
// regs during phase-0 staging; ones-MFMA softmax denominator.
// R18: XCD-chunked swizzle — logical blocks 4h..4h+3 share one head's 64KB
// K/V; remap gid=(phys&7)*128+phys>>3 (bijective, 1024=8x128) co-locates
// them on one XCD -> 3 of 4 K/V stagings hit the local L2.
__global__ __launch_bounds__(256, 4) void attn_kernel(
    const bf16_t* __restrict__ Qh, const bf16_t* __restrict__ Kh,
    const bf16_t* __restrict__ Vh, bf16_t* __restrict__ Oa) {
  __shared__ bf16_t Ks[256 * 32];      // K half (16KB)
  __shared__ bf16_t Vs[32 * 264];      // V half, rows padded to 264 (16.5KB)
  int pg = blockIdx.x;
  int gid = (pg & 7) * 128 + (pg >> 3);  // R18 XCD-chunked swizzle
  int ms = gid & 3, head = gid >> 2;
  int h = head & 7, g = (head >> 3) & 7, b = head >> 6;
  int tid = threadIdx.x, lane = tid & 63, wid = tid >> 6;
  int quad = lane >> 4, l16 = lane & 15;

  const bf16_t* Kg = Kh + (long long)head * (Mm * HDd);
  const bf16_t* Vg = Vh + (long long)head * (Mm * HDd);
  const bf16_t* Qg = Qh + (long long)head * (Mm * HDd) + (ms * 128 + wid * 32) * HDd;

  // Q fragments: phase-invariant, loaded once.
  bf16x8 qa = *(const bf16x8*)&Qg[l16 * HDd + quad * 8];
  bf16x8 qb = *(const bf16x8*)&Qg[(16 + l16) * HDd + quad * 8];

  bf16x8 ones;
#pragma unroll
  for (int i = 0; i < 8; ++i) ones[i] = (bf16_t)1.0f;

  // Permuted K-row gather: tile0 rows 8q+r, tile1 rows 8q+4+r
  int rp0 = ((l16 >> 2) << 3) | (l16 & 3);
  const bf16_t* Kp0 = &Ks[rp0 * HDd + quad * 8];        // +c*1024 per chunk
  const bf16_t* Kp1 = Kp0 + 4 * HDd;
  const bf16_t* VsL = &Vs[l16 * 264 + quad * 8];
  const bf16_t* VsH = &Vs[(16 + l16) * 264 + quad * 8];
  const f32x4 zero = (f32x4){0.f, 0.f, 0.f, 0.f};

  f32x4 oLa = zero, oHa = zero, oLb = zero, oHb = zero;
  f32x4 ra = zero, rb = zero;

  auto inner = [&]() {
#pragma unroll
    for (int c = 0; c < 8; ++c) {       // 32 K-rows per chunk
      int nb = c * 32;
      bf16x8 kf0 = *(const bf16x8*)&Kp0[nb * HDd];
      bf16x8 kf1 = *(const bf16x8*)&Kp1[nb * HDd];
      f32x4 sa0 = __builtin_amdgcn_mfma_f32_16x16x32_bf16(kf0, qa, zero, 0, 0, 0);
      f32x4 sa1 = __builtin_amdgcn_mfma_f32_16x16x32_bf16(kf1, qa, zero, 0, 0, 0);
      f32x4 sb0 = __builtin_amdgcn_mfma_f32_16x16x32_bf16(kf0, qb, zero, 0, 0, 0);
      f32x4 sb1 = __builtin_amdgcn_mfma_f32_16x16x32_bf16(kf1, qb, zero, 0, 0, 0);
      bf16x8 pa, pb;
#pragma unroll
      for (int r = 0; r < 4; ++r) {
        pa[r] = (bf16_t)__builtin_exp2f(sa0[r]);
        pa[4 + r] = (bf16_t)__builtin_exp2f(sa1[r]);
        pb[r] = (bf16_t)__builtin_exp2f(sb0[r]);
        pb[4 + r] = (bf16_t)__builtin_exp2f(sb1[r]);
      }
      bf16x8 vL = *(const bf16x8*)&VsL[nb];
      bf16x8 vH = *(const bf16x8*)&VsH[nb];
      oLa = __builtin_amdgcn_mfma_f32_16x16x32_bf16(vL, pa, oLa, 0, 0, 0);
      oHa = __builtin_amdgcn_mfma_f32_16x16x32_bf16(vH, pa, oHa, 0, 0, 0);
      oLb = __builtin_amdgcn_mfma_f32_16x16x32_bf16(vL, pb, oLb, 0, 0, 0);
      oHb = __builtin_amdgcn_mfma_f32_16x16x32_bf16(vH, pb, oHb, 0, 0, 0);
      ra = __builtin_amdgcn_mfma_f32_16x16x32_bf16(ones, pa, ra, 0, 0, 0);
      rb = __builtin_amdgcn_mfma_f32_16x16x32_bf16(ones, pb, rb, 0, 0, 0);
    }
  };

  // ---- phase 0 staging (block start: LDS cold, no WAR barrier needed)
#pragma unroll
  for (int it = 0; it < 4; ++it) {
    int ch = wid * 4 + it;
    load_lds16(&Kg[ch * 512 + lane * 8], &Ks[ch * 512]);
  }
  bf16x8 vcur[4], vnxt[4];
#pragma unroll
  for (int i = 0; i < 4; ++i) {
    int idx = i * 256 + tid;
    int d = idx >> 5, c16 = idx & 31;
    vcur[i] = *(const bf16x8*)&Vg[d * Mm + c16 * 8];
    vnxt[i] = *(const bf16x8*)&Vg[d * Mm + 256 + c16 * 8];  // prefetch
  }
#pragma unroll
  for (int i = 0; i < 4; ++i) {
    int idx = i * 256 + tid;
    int d = idx >> 5, c16 = idx & 31;
    *(bf16x8*)&Vs[d * 264 + c16 * 8] = vcur[i];
  }
  __syncthreads();
  inner();                              // phase 0
  __syncthreads();                      // Ks/Vs WAR
  // ---- phase 1 staging (V already in regs)
#pragma unroll
  for (int it = 0; it < 4; ++it) {
    int ch = wid * 4 + it;
    load_lds16(&Kg[8192 + ch * 512 + lane * 8], &Ks[ch * 512]);
  }
#pragma unroll
  for (int i = 0; i < 4; ++i) {
    int idx = i * 256 + tid;
    int d = idx >> 5, c16 = idx & 31;
    *(bf16x8*)&Vs[d * 264 + c16 * 8] = vnxt[i];
  }
  __syncthreads();
  inner();                              // phase 1

  // denom: every component of ra equals sum_n P[n][l16]
  float inva = 1.f / ra[0], invb = 1.f / rb[0];

  // O^T in C-layout: lane holds O^T[d=quad*4+r (+0/16)][m=l16]
  long long orowa =
      ((long long)(b * Nn + g * Mm + ms * 128 + wid * 32 + l16)) * Cc + h * HDd;
  long long orowb = orowa + 16 * Cc;
  bf16x4 wLa, wHa, wLb, wHb;
#pragma unroll
  for (int r = 0; r < 4; ++r) {
    wLa[r] = (bf16_t)(oLa[r] * inva);
    wHa[r] = (bf16_t)(oHa[r] * inva);
    wLb[r] = (bf16_t)(oLb[r] * invb);
    wHb[r] = (bf16_t)(oHb[r] * invb);
  }
  *(bf16x4*)&Oa[orowa + quad * 4] = wLa;
  *(bf16x4*)&Oa[orowa + 16 + quad * 4] = wHa;
  *(bf16x4*)&Oa[orowb + quad * 4] = wLb;
  *(bf16x4*)&Oa[orowb + 16 + quad * 4] = wHb;
}

// ----------------------------------------------------------------- proj GEMM
// out[b][i][n] = sum_c Wp[i][c]*Oa[b*N+n][c] + bias[i]; z-batched over b.
// R15: 64x64 tile, grid dim3(64,4,4) = 1024 blocks = 4/CU, 16KB LDS, acc[4].
// (Oa-tile sharers differ by linear id 64 ≡ 0 mod 8 -> same XCD already.)
__global__ __launch_bounds__(256, 4) void proj_kernel(
    const bf16_t* __restrict__ Wp, const bf16_t* __restrict__ Oa,
    float* __restrict__ out, const float* __restrict__ bias) {
  __shared__ bf16_t As[2][64 * 32];    // 8 KB total
  __shared__ bf16_t Bs[2][64 * 32];    // 8 KB total
  int tid = threadIdx.x, lane = tid & 63, wid = tid >> 6;
  int quad = lane >> 4, l16 = lane & 15;
  int z = blockIdx.z;
  const bf16_t* Bt = Oa + (long long)z * Nn * Cc;
  int m0 = blockIdx.y * 64, n0 = blockIdx.x * 64;

  f32x4 acc[4];
#pragma unroll
  for (int i = 0; i < 4; ++i) acc[i] = (f32x4){0.f, 0.f, 0.f, 0.f};

  int scol = (lane & 3) * 8;
  int arow = lane >> 2;
  auto stage = [&](int bufi, int k0) {
    load_lds16(&Wp[(long long)(m0 + wid * 16 + arow) * Cc + k0 + scol],
               &As[bufi][wid * 512]);
    load_lds16(&Bt[(long long)(n0 + wid * 16 + arow) * Cc + k0 + scol],
               &Bs[bufi][wid * 512]);
  };

  stage(0, 0);
  __syncthreads();
  for (int t = 0; t < 8; ++t) {
    if (t < 7) stage((t + 1) & 1, (t + 1) * 32);
    const bf16_t* Ap = As[t & 1];
    const bf16_t* Bp = Bs[t & 1];
    bf16x8 a[4], b;
#pragma unroll
    for (int i = 0; i < 4; ++i)
      a[i] = *(const bf16x8*)&Ap[(i * 16 + l16) * 32 + quad * 8];
    b = *(const bf16x8*)&Bp[(wid * 16 + l16) * 32 + quad * 8];
#pragma unroll
    for (int i = 0; i < 4; ++i)
      acc[i] = __builtin_amdgcn_mfma_f32_16x16x32_bf16(a[i], b, acc[i], 0, 0, 0);
    __syncthreads();
  }

#pragma unroll
  for (int i = 0; i < 4; ++i) {
    int col = n0 + wid * 16 + l16;
#pragma unroll
    for (int r = 0; r < 4; ++r) {
      int row = m0 + i * 16 + quad * 4 + r;
      out[(long long)z * (Cc * Nn) + (long long)row * Nn + col] =
          acc[i][r] + bias[row];
    }
  }
}

// ------------------------------------------------------------------- launcher
extern "C" void kernel_launch(void* const* d_in, const int* in_sizes, int n_in,
                              void* d_out, int out_size, void* d_ws, size_t ws_size,
                              hipStream_t stream) {
  (void)in_sizes; (void)n_in; (void)out_size; (void)ws_size;
  const float* x = (const float*)d_in[0];
  const float* w_qkv = (const float*)d_in[1];
  const float* w_proj = (const float*)d_in[2];
  const float* b_proj = (const float*)d_in[3];
  float* out = (float*)d_out;

  char* ws = (char*)d_ws;
  bf16_t* xT  = (bf16_t*)(ws);                 // [B][N][C]     8,388,608 B
  bf16_t* wqb = (bf16_t*)(ws + 8388608);       // [768][256]      393,216 B
  bf16_t* wpb = (bf16_t*)(ws + 8781824);       // [256][256]      131,072 B
  bf16_t* Qh  = (bf16_t*)(ws + 8912896);       // [256][512][32] 8,388,608 B
  bf16_t* Kh  = (bf16_t*)(ws + 17301504);      // [256][512][32] 8,388,608 B
  bf16_t* Vh  = (bf16_t*)(ws + 25690112);      // [256][32][512] 8,388,608 B
  bf16_t* Oa  = (bf16_t*)(ws + 34078720);      // [B*N][256]     8,388,608 B

  prep_kernel<<<1792, 256, 0, stream>>>(x, xT, w_qkv, w_proj, wqb, wpb);
  qkv_gemm_kernel<<<768, 256, 0, stream>>>(xT, wqb, Qh, Kh, Vh);
  attn_kernel<<<1024, 256, 0, stream>>>(Qh, Kh, Vh, Oa);
  proj_kernel<<<dim3(64, 4, 4), 256, 0, stream>>>(wpb, Oa, out, b_proj);
}